// Round 16
// baseline (49.249 us; speedup 1.0000x reference)
//
#include <hip/hip_runtime.h>
#include <math.h>

#define NTOK 16384
#define DK   2048
#define NEXP 64

typedef float f32x4 __attribute__((ext_vector_type(4)));
typedef int   i32x4 __attribute__((ext_vector_type(4)));
typedef short s16x8 __attribute__((ext_vector_type(8)));

// ---- scalar RTNE fp32->bf16 ----
__device__ __forceinline__ unsigned short f2bf(float f) {
    union { float f; unsigned u; } v; v.f = f;
    unsigned r = (v.u + 0x7FFFu + ((v.u >> 16) & 1u)) >> 16;
    return (unsigned short)r;
}
__device__ __forceinline__ float bf2f(unsigned short h) {
    union { unsigned u; float f; } v; v.u = ((unsigned)h) << 16;
    return v.f;
}

// Pre-kernel: 3-way bf16 split of W, PACKED in MFMA B-fragment order (r11):
// ws[w][c][n][p][lane][8 shorts], lane = g*16 + rr holds expert 16n+rr,
// k = w*512 + c*32 + g*8..+8, plane p. 1 KB contiguous per (c,n,p) frag.
__global__ __launch_bounds__(256) void wsplit_pack(const float* __restrict__ Wg,
                                                   unsigned short* __restrict__ ws) {
    const int t  = blockIdx.x * 256 + threadIdx.x;  // 16384 = 64 experts x 256 k-octets
    const int e  = t >> 8;
    const int k  = (t & 255) * 8;
    const int w  = k >> 9;
    const int c  = (k >> 5) & 15;
    const int g  = (k >> 3) & 3;
    const int rr = e & 15;
    const int n  = e >> 4;
    const int lane = g * 16 + rr;

    const float* src = Wg + (size_t)e * DK + k;
    unsigned short p0[8], p1[8], p2[8];
    #pragma unroll
    for (int j = 0; j < 8; ++j) {
        const float f = src[j];
        p0[j] = f2bf(f);  const float r1 = f - bf2f(p0[j]);
        p1[j] = f2bf(r1); const float r2 = r1 - bf2f(p1[j]);
        p2[j] = f2bf(r2);
    }
    const size_t base = ((((size_t)w * 16 + c) * 4 + n) * 3) * 512 + (size_t)lane * 8;
    *(s16x8*)(ws + base)        = *(s16x8*)p0;
    *(s16x8*)(ws + base + 512)  = *(s16x8*)p1;
    *(s16x8*)(ws + base + 1024) = *(s16x8*)p2;
}

// Async global->LDS, 16B/lane (dst wave-uniform; HW adds lane*16).
__device__ __forceinline__ void gload_lds16(const float* src, float* dst) {
    __builtin_amdgcn_global_load_lds(
        (const __attribute__((address_space(1))) void*)src,
        (__attribute__((address_space(3))) void*)dst, 16, 0, 0);
}

__device__ __forceinline__ unsigned cvtpk(float lo, float hi) {
    unsigned r;
    asm("v_cvt_pk_bf16_f32 %0, %1, %2" : "=v"(r) : "v"(lo), "v"(hi));
    return r;
}

#define SPLIT2(F0, F1, O0, O1, O2) { \
    const unsigned q0 = cvtpk((F0), (F1)); \
    const float s0 = (F0) - __builtin_bit_cast(float, q0 << 16); \
    const float s1 = (F1) - __builtin_bit_cast(float, q0 & 0xFFFF0000u); \
    const unsigned q1 = cvtpk(s0, s1); \
    const float t0 = s0 - __builtin_bit_cast(float, q1 << 16); \
    const float t1 = s1 - __builtin_bit_cast(float, q1 & 0xFFFF0000u); \
    O0 = (int)q0; O1 = (int)q1; O2 = (int)cvtpk(t0, t1); }

// x staging (coalesced + XOR bank-swizzle, both-sides involution, r15):
// 4 instrs cover [32 tok][32 k]; each = 8 rows x 128 B dense segments.
#define STAGE_X(c, BUF) { \
    _Pragma("unroll") for (int it = 0; it < 4; ++it) \
        gload_lds16(xsrc + (size_t)it * 8 * DK + (size_t)(c) * 32, \
                    &xs[w][BUF][it * 256]); }

#define ISSUE_B(BS, c) { \
    _Pragma("unroll") for (int n = 0; n < 4; ++n) \
        _Pragma("unroll") for (int p = 0; p < 3; ++p) \
            BS[n][p] = *(const i32x4*)(wbase + ((size_t)(c) * 12 + n * 3 + p) * 512); }

// A-frags from LDS with the inverse swizzle on the granule slot.
#define CONV_LDS(BUF) { \
    _Pragma("unroll") for (int m = 0; m < 2; ++m) { \
        const int row = rr + 16 * m; \
        const int sw  = row & 7; \
        const float4 xa0 = *(const float4*)&xs[w][BUF][row * 32 + (((g * 2 + 0) ^ sw) << 2)]; \
        const float4 xa1 = *(const float4*)&xs[w][BUF][row * 32 + (((g * 2 + 1) ^ sw) << 2)]; \
        SPLIT2(xa0.x, xa0.y, A[m][0].x, A[m][1].x, A[m][2].x); \
        SPLIT2(xa0.z, xa0.w, A[m][0].y, A[m][1].y, A[m][2].y); \
        SPLIT2(xa1.x, xa1.y, A[m][0].z, A[m][1].z, A[m][2].z); \
        SPLIT2(xa1.z, xa1.w, A[m][0].w, A[m][1].w, A[m][2].w); } }

#define MFMA_TERM(pa, pb, BS) { \
    _Pragma("unroll") for (int m = 0; m < 2; ++m) \
        _Pragma("unroll") for (int n = 0; n < 4; ++n) \
            acc[m][n] = __builtin_amdgcn_mfma_f32_16x16x32_bf16( \
                __builtin_bit_cast(s16x8, A[m][pa]), \
                __builtin_bit_cast(s16x8, BS[n][pb]), acc[m][n], 0, 0, 0); }

// 6 terms: (0,0),(0,1),(1,0),(1,1),(0,2),(2,0) -> logit exact to ~2^-24 rel
#define MFMA_ALL(BS) \
    MFMA_TERM(0, 0, BS) MFMA_TERM(0, 1, BS) MFMA_TERM(1, 0, BS) \
    MFMA_TERM(1, 1, BS) MFMA_TERM(0, 2, BS) MFMA_TERM(2, 0, BS)

// Asymmetric-depth phase. Per phase p (issue order: B(p+2) THEN X(p+3)),
// steady-state retire math: outstanding at wait = [X(c),B(c),X(c+1),B(c+1),
// X(c+2)] = 36; vmcnt(20) retires exactly through {X(c),B(c)} -> x gets a
// 3-phase (~1500 cyc) HBM cover, B a 2-phase L2 cover. r12's depth-3 null
// was confounded by the scattered-x throughput limit (fixed in r14).
#define PHASE(c, XBUF, BS, NCNT, DO_B, DO_X) { \
    asm volatile("s_waitcnt vmcnt(" #NCNT ")" ::: "memory"); \
    __builtin_amdgcn_sched_barrier(0); \
    CONV_LDS(XBUF); \
    MFMA_ALL(BS); \
    if (DO_B) ISSUE_B(BS, (c) + 2); \
    if (DO_X) STAGE_X((c) + 3, XBUF); \
    __builtin_amdgcn_sched_barrier(0); }

__global__ __launch_bounds__(256, 2) void topk_router_kernel(
    const float* __restrict__ x,            // [NTOK][DK] fp32
    const unsigned short* __restrict__ ws,  // packed B frags (768 KB)
    float* __restrict__ out)                // [NTOK*2] idx (as float) ++ [NTOK*2] w
{
    // xs: wave-private x staging [4 waves][3 bufs][32 tok x 32 k] = 48 KB.
    // lg overlays the same smem after the epilogue barrier (8704 floats).
    __shared__ float smem[12288];
    float (*xs)[3][1024] = (float (*)[3][1024])smem;
    float (*lg)[32][68]  = (float (*)[32][68])smem;

    const int tid  = threadIdx.x;
    const int w    = tid >> 6;              // wave 0..3 == K-quarter
    const int lane = tid & 63;
    const int rr   = lane & 15;
    const int g    = lane >> 4;
    const int tok0 = blockIdx.x * 32;

    // staging lanes: row lt (+8*it), slot lq; pre-swizzled source granule lq^lt
    const int lt = lane >> 3;
    const int lq = lane & 7;
    const float* xsrc = x + (size_t)(tok0 + lt) * DK + w * 512 + ((lq ^ lt) * 4);
    // B: packed frags for this wave's K-quarter; 1 KB contiguous per frag.
    const unsigned short* wbase = ws + (size_t)w * 98304 + (size_t)lane * 8;

    f32x4 acc[2][4];
    #pragma unroll
    for (int m = 0; m < 2; ++m)
        #pragma unroll
        for (int n = 0; n < 4; ++n) acc[m][n] = (f32x4){0.f, 0.f, 0.f, 0.f};

    i32x4 B0[4][3], B1[4][3];
    i32x4 A[2][3];

    // ---- prologue, exact issue order X0,B0,X1,B1,X2 (36 VMEM in flight) ----
    STAGE_X(0, 0);
    ISSUE_B(B0, 0);
    STAGE_X(1, 1);
    ISSUE_B(B1, 1);
    STAGE_X(2, 2);

    // ---- main: phases 0..11 (x bufs mod 3, B regs mod 2 -> period 6) ----
    #pragma unroll 1
    for (int c = 0; c < 12; c += 6) {
        PHASE(c + 0, 0, B0, 20, 1, 1);
        PHASE(c + 1, 1, B1, 20, 1, 1);
        PHASE(c + 2, 2, B0, 20, 1, 1);
        PHASE(c + 3, 0, B1, 20, 1, 1);
        PHASE(c + 4, 1, B0, 20, 1, 1);
        PHASE(c + 5, 2, B1, 20, 1, 1);
    }
    // ---- tail: phases 12..15, exact-counted drain ----
    PHASE(12, 0, B0, 20, 1, 1);   // issues B(14)->B0, X(15)->buf0
    PHASE(13, 1, B1, 20, 1, 0);   // issues B(15)->B1
    PHASE(14, 2, B0, 16, 0, 0);
    PHASE(15, 0, B1,  0, 0, 0);

    // ---- combine 4 K-quarters (the only barriers) ----
    __syncthreads();
    #pragma unroll
    for (int m = 0; m < 2; ++m)
        #pragma unroll
        for (int n = 0; n < 4; ++n)
            #pragma unroll
            for (int r = 0; r < 4; ++r)
                lg[w][m * 16 + g * 4 + r][n * 16 + rr] = acc[m][n][r];
    __syncthreads();

    // ---- top-2 per token: wave w -> tokens w*8..+7, lane = expert ----
    #pragma unroll 1
    for (int t = 0; t < 8; ++t) {
        const int tok = w * 8 + t;
        const float v = lg[0][tok][lane] + lg[1][tok][lane]
                      + lg[2][tok][lane] + lg[3][tok][lane];

        // top-1 (tie -> lower index, matching lax.top_k)
        float m1 = v; int i1 = lane;
        #pragma unroll
        for (int off = 32; off > 0; off >>= 1) {
            float ov = __shfl_xor(m1, off);
            int   oi = __shfl_xor(i1, off);
            if (ov > m1 || (ov == m1 && oi < i1)) { m1 = ov; i1 = oi; }
        }
        // top-2: mask out winner
        float m2 = (lane == i1) ? -INFINITY : v; int i2 = lane;
        #pragma unroll
        for (int off = 32; off > 0; off >>= 1) {
            float ov = __shfl_xor(m2, off);
            int   oi = __shfl_xor(i2, off);
            if (ov > m2 || (ov == m2 && oi < i2)) { m2 = ov; i2 = oi; }
        }

        if (lane == 0) {
            const int gtok = tok0 + tok;
            // softmax denom cancels: w1 = 1/(1+e^{l2-l1}), w2 = 1 - w1
            const float e  = expf(m2 - m1);
            const float w1 = 1.0f / (1.0f + e);
            const float w2 = e / (1.0f + e);
            out[gtok * 2 + 0] = (float)i1;
            out[gtok * 2 + 1] = (float)i2;
            out[NTOK * 2 + gtok * 2 + 0] = w1;
            out[NTOK * 2 + gtok * 2 + 1] = w2;
        }
    }
}

extern "C" void kernel_launch(void* const* d_in, const int* in_sizes, int n_in,
                              void* d_out, int out_size, void* d_ws, size_t ws_size,
                              hipStream_t stream) {
    const float* x  = (const float*)d_in[0];
    const float* Wg = (const float*)d_in[1];
    float* out = (float*)d_out;
    unsigned short* ws = (unsigned short*)d_ws;   // 768 KB packed B
    hipLaunchKernelGGL(wsplit_pack, dim3(64), dim3(256), 0, stream, Wg, ws);
    // 512 blocks x 256 thr = 2048 waves (2/SIMD): x 3-deep via LDS (HBM cover),
    // B 2-deep in regs (L2 cover), counted vmcnt(20), no in-loop barriers.
    hipLaunchKernelGGL(topk_router_kernel, dim3(NTOK / 32), dim3(256), 0, stream,
                       x, ws, out);
}